// Round 21
// baseline (1164.376 us; speedup 1.0000x reference)
//
#include <hip/hip_runtime.h>

typedef _Float16 half8 __attribute__((ext_vector_type(8)));
typedef float f32x4 __attribute__((ext_vector_type(4)));

#define TT 48
#define BT 32
#define NSEQ 16384
#define NGRP (NSEQ / BT)           // 512 groups
#define NTHR 1024                  // 16 waves
#define MAXGRID 512
#define H0_SLICE (TT * BT * 136)   // f16 elems per block ws slice (417792 B)

// h0w layout: [t][d][b][j], stride per t = 4352 f16
struct __align__(16) Smem {
  float gates[272 * 33];        // 35904 B  [gate][batch(+pad)]
  _Float16 A[32 * 232];         // 14848 B  A panel (L0 view: [32][136])
  union {
    _Float16 bx[7 * 64 * 8];    //  7168 B  LDS B-fragments for tile 16 (during passes)
    float ysc[160];             //  FC combine scratch (after passes)
  } u;
  float fcwt[2][340];           //  2720 B  staged fcw slice, double-buffered (L1 only)
};                              // 60640 B static LDS

__device__ __forceinline__ float fast_rcp(float v) { return __builtin_amdgcn_rcpf(v); }
__device__ __forceinline__ float sigm(float v)  { return fast_rcp(1.f + __expf(-v)); }
__device__ __forceinline__ float tanh_s(float v){ return 1.f - 2.f * fast_rcp(1.f + __expf(2.f * v)); }

// One (layer, dir) recurrence over 32 sequences, 16 waves.
// Wave w owns reg B-tile w; tile 16 via LDS bx: wave 0 lo-half, wave 1 hi-half.
// Elementwise: thread owns b = tid>>5, j = (tid&31) + 32q (+ j=64+(tid&31) if <4).
template <int LAYER>
__device__ __forceinline__ void pass_lstm(Smem& s, const int d,
    const float* __restrict__ Wih, const float* __restrict__ Whh,
    const float* __restrict__ bih, const float* __restrict__ bhh,
    const float* __restrict__ xg,  const float* __restrict__ fcw,
    _Float16* __restrict__ h0w, float (&yk)[5])
{
  constexpr int AW    = LAYER ? 232 : 136;  // A row stride (f16)
  constexpr int KS    = LAYER ? 7 : 4;      // K chunks of 32 (224 / 128)
  constexpr int INW   = LAYER ? 136 : 34;   // non-recurrent width
  constexpr int BIASC = INW + 68;           // bias-one column (204 / 102)
  constexpr int HOFF  = LAYER ? 136 : 34;   // h slot base in A row

  const int tid = threadIdx.x;
  const int ln = tid & 63, wid = tid >> 6;  // wid 0..15
  const int lr = ln & 15, lq = ln >> 4;

  float* gates = s.gates;
  _Float16* A  = s.A;

  // ---- reg B fragments: ONE tile per wave (KS*4 <= 28 VGPR) ----
  half8 Bf[KS];
  {
    const int g = wid * 16 + lr;
    #pragma unroll
    for (int kk = 0; kk < KS; ++kk) {
      half8 v;
      #pragma unroll
      for (int j = 0; j < 8; ++j) {
        const int k = kk * 32 + lq * 8 + j;
        float wv = 0.f;
        if (k < INW) wv = Wih[g * INW + k];
        else if (k < BIASC) wv = Whh[g * 68 + (k - INW)];
        else if (k == BIASC) wv = bih[g] + bhh[g];
        v[j] = (_Float16)wv;
      }
      Bf[kk] = v;
    }
  }
  // ---- LDS B fragments for tile 16 ----
  if (tid < KS * 64) {
    const int kk = tid >> 6, l2 = tid & 63;
    const int g = 256 + (l2 & 15);
    half8 v;
    #pragma unroll
    for (int j = 0; j < 8; ++j) {
      const int k = kk * 32 + ((l2 >> 4) & 3) * 8 + j;
      float wv = 0.f;
      if (k < INW) wv = Wih[g * INW + k];
      else if (k < BIASC) wv = Whh[g * 68 + (k - INW)];
      else if (k == BIASC) wv = bih[g] + bhh[g];
      v[j] = (_Float16)wv;
    }
    *(half8*)&s.u.bx[tid * 8] = v;
  }

  float cst[3];
  #pragma unroll
  for (int q = 0; q < 3; ++q) cst[q] = 0.f;

  // ---- staging offsets (t-independent); 1088 tasks = 1024 + 64 extras ----
  int sgo0, sao0, sgo1, sao1;
  if constexpr (LAYER == 0) {
    { const int b = tid / 34, i = tid % 34;
      sgo0 = b * (TT * 34) + i;  sao0 = b * 136 + i; }
    { const int t1 = (tid < 64) ? (tid + 1024) : 1024, b = t1 / 34, i = t1 % 34;
      sgo1 = b * (TT * 34) + i;  sao1 = b * 136 + i; }
  } else {
    { const int dd = tid / 544, r = tid % 544, b = r / 17, c = r % 17;
      sgo0 = dd * 2176 + b * 68 + c * 4;  sao0 = b * 232 + dd * 68 + c * 4; }
    { const int t1 = (tid < 64) ? (tid + 1024) : 1024, dd = t1 / 544, r = t1 % 544,
        b = r / 17, c = r % 17;
      sgo1 = dd * 2176 + b * 68 + c * 4;  sao1 = b * 232 + dd * 68 + c * 4; }
  }
  int fk2 = 0, fj = 0;
  if constexpr (LAYER) { if (tid < 340) { fk2 = tid / 68; fj = tid % 68; } }

  // ---- prologue: zero A (4*AW uint4 <= 928 < 1024), bias col, stage step 0 ----
  if (tid < AW * 4) ((uint4*)A)[tid] = (uint4){0, 0, 0, 0};
  __syncthreads();
  if (tid < 32) A[tid * AW + BIASC] = (_Float16)1.f;
  const int t0 = d ? (TT - 1) : 0;
  if constexpr (LAYER == 0) {
    A[sao0] = (_Float16)xg[sgo0 + t0 * 34];
    if (tid < 64) A[sao1] = (_Float16)xg[sgo1 + t0 * 34];
  } else {
    *(uint2*)&A[sao0] = *(const uint2*)&h0w[sgo0 + t0 * 4352];
    if (tid < 64) *(uint2*)&A[sao1] = *(const uint2*)&h0w[sgo1 + t0 * 4352];
    if (tid < 340) s.fcwt[0][tid] = fcw[fk2 * 6528 + t0 * 136 + d * 68 + fj];
  }
  __syncthreads();

  #pragma unroll 1
  for (int st = 0; st < TT; ++st) {
    const int t  = d ? (TT - 1 - st) : st;
    const int tn = d ? (t - 1) : (t + 1);

    // ---- prefetch next step's staging into registers ----
    float xp0 = 0.f, xp1 = 0.f, fwp = 0.f;
    uint2 hp0 = {0, 0}, hp1 = {0, 0};
    if (st < TT - 1) {
      if constexpr (LAYER == 0) {
        xp0 = xg[sgo0 + tn * 34];
        if (tid < 64) xp1 = xg[sgo1 + tn * 34];
      } else {
        hp0 = *(const uint2*)&h0w[sgo0 + tn * 4352];
        if (tid < 64) hp1 = *(const uint2*)&h0w[sgo1 + tn * 4352];
        if (tid < 340) fwp = fcw[fk2 * 6528 + tn * 136 + d * 68 + fj];
      }
    }

    // ---- MFMA: gates(32x272) = A(32xK).B(Kx272); wave owns 1 tile, lo+hi halves ----
    f32x4 aL = {0.f,0.f,0.f,0.f}, aH = {0.f,0.f,0.f,0.f};
    f32x4 a2 = {0.f,0.f,0.f,0.f};   // tile 16: wave 0 -> lo half, wave 1 -> hi half
    #pragma unroll
    for (int kk = 0; kk < KS; ++kk) {
      const half8 alo = *(const half8*)&A[lr * AW + kk * 32 + lq * 8];
      const half8 ahi = *(const half8*)&A[(lr + 16) * AW + kk * 32 + lq * 8];
      aL = __builtin_amdgcn_mfma_f32_16x16x32_f16(alo, Bf[kk], aL, 0, 0, 0);
      aH = __builtin_amdgcn_mfma_f32_16x16x32_f16(ahi, Bf[kk], aH, 0, 0, 0);
      if (wid < 2) {
        const half8 bb = *(const half8*)&s.u.bx[(kk * 64 + ln) * 8];
        const half8 av = (wid == 0) ? alo : ahi;
        a2 = __builtin_amdgcn_mfma_f32_16x16x32_f16(av, bb, a2, 0, 0, 0);
      }
    }
    // C/D: col = lr (gate within tile), row = lq*4+r (batch; +16 for hi tile)
    {
      const int g0 = wid * 16 + lr;
      #pragma unroll
      for (int r = 0; r < 4; ++r) {
        gates[g0 * 33 + lq * 4 + r]      = aL[r];
        gates[g0 * 33 + 16 + lq * 4 + r] = aH[r];
      }
      if (wid < 2) {
        #pragma unroll
        for (int r = 0; r < 4; ++r)
          gates[(256 + lr) * 33 + 16 * wid + lq * 4 + r] = a2[r];
      }
    }
    __syncthreads();

    // ---- elementwise cell update: b-uniform ownership (<=3 pairs/thread) ----
    {
      const int b = tid >> 5, jb = tid & 31;
      #pragma unroll
      for (int q = 0; q < 3; ++q) {
        if (q < 2 || jb < 4) {
          const int j = (q < 2) ? (jb + 32 * q) : (64 + jb);
          const int gq = j * 33 + b;
          const float gi = gates[gq];
          const float gf = gates[gq + 2244];    // (68+j)*33+b
          const float gg = gates[gq + 4488];
          const float go = gates[gq + 6732];
          const float ii = sigm(gi), ff = sigm(gf), g2 = tanh_s(gg), oo = sigm(go);
          const float cc = ff * cst[q] + ii * g2;
          cst[q] = cc;
          const float h = oo * tanh_s(cc);
          const _Float16 h16 = (_Float16)h;
          A[b * AW + HOFF + j] = h16;
          if constexpr (LAYER == 0) {
            h0w[t * 4352 + d * 2176 + b * 68 + j] = h16;
          } else {
            #pragma unroll
            for (int k = 0; k < 5; ++k) yk[k] += h * s.fcwt[st & 1][k * 68 + j];
          }
        }
      }
    }
    // ---- staging writes for next step ----
    if (st < TT - 1) {
      if constexpr (LAYER == 0) {
        A[sao0] = (_Float16)xp0;
        if (tid < 64) A[sao1] = (_Float16)xp1;
      } else {
        *(uint2*)&A[sao0] = hp0;
        if (tid < 64) *(uint2*)&A[sao1] = hp1;
        if (tid < 340) s.fcwt[(st + 1) & 1][tid] = fwp;
      }
    }
    __syncthreads();
  }
}

__global__ __attribute__((amdgpu_flat_work_group_size(NTHR, NTHR)))
void lstm_fc_kernel(
    const float* __restrict__ x,
    const float* __restrict__ Wih0f, const float* __restrict__ Whh0f,
    const float* __restrict__ bih0f, const float* __restrict__ bhh0f,
    const float* __restrict__ Wih0b, const float* __restrict__ Whh0b,
    const float* __restrict__ bih0b, const float* __restrict__ bhh0b,
    const float* __restrict__ Wih1f, const float* __restrict__ Whh1f,
    const float* __restrict__ bih1f, const float* __restrict__ bhh1f,
    const float* __restrict__ Wih1b, const float* __restrict__ Whh1b,
    const float* __restrict__ bih1b, const float* __restrict__ bhh1b,
    const float* __restrict__ fcw, const float* __restrict__ fcb,
    float* __restrict__ out, _Float16* __restrict__ ws)
{
  __shared__ Smem s;
  const int tid = threadIdx.x;
  _Float16* h0w = ws + (size_t)blockIdx.x * H0_SLICE;

  for (int grp = blockIdx.x; grp < NGRP; grp += gridDim.x) {
    const float* xg = x + (size_t)grp * (BT * TT * 34);
    float yk[5] = {0.f, 0.f, 0.f, 0.f, 0.f};

    pass_lstm<0>(s, 0, Wih0f, Whh0f, bih0f, bhh0f, xg, nullptr, h0w, yk);
    pass_lstm<0>(s, 1, Wih0b, Whh0b, bih0b, bhh0b, xg, nullptr, h0w, yk);
    pass_lstm<1>(s, 0, Wih1f, Whh1f, bih1f, bhh1f, nullptr, fcw, h0w, yk);
    pass_lstm<1>(s, 1, Wih1b, Whh1b, bih1b, bhh1b, nullptr, fcw, h0w, yk);

    // ---- FC epilogue: butterfly over the 32 threads sharing b, then combine ----
    #pragma unroll
    for (int m = 1; m < 32; m <<= 1) {
      #pragma unroll
      for (int k = 0; k < 5; ++k) yk[k] += __shfl_xor(yk[k], m, 64);
    }
    __syncthreads();   // all passes done before overwriting bx-union with ysc
    if ((tid & 31) == 0) {
      #pragma unroll
      for (int k = 0; k < 5; ++k) s.u.ysc[(tid >> 5) * 5 + k] = yk[k];
    }
    __syncthreads();
    if (tid < BT * 5) {
      const int k = tid % 5;
      out[(size_t)(grp * BT) * 5 + tid] = s.u.ysc[tid] + fcb[k];
    }
    __syncthreads();
  }
}

extern "C" void kernel_launch(void* const* d_in, const int* in_sizes, int n_in,
                              void* d_out, int out_size, void* d_ws, size_t ws_size,
                              hipStream_t stream) {
  (void)in_sizes; (void)n_in; (void)out_size;
  static_assert(sizeof(Smem) <= 64 * 1024, "LDS budget");

  const float* x     = (const float*)d_in[0];
  const float* Wih0f = (const float*)d_in[1];
  const float* Whh0f = (const float*)d_in[2];
  const float* bih0f = (const float*)d_in[3];
  const float* bhh0f = (const float*)d_in[4];
  const float* Wih0b = (const float*)d_in[5];
  const float* Whh0b = (const float*)d_in[6];
  const float* bih0b = (const float*)d_in[7];
  const float* bhh0b = (const float*)d_in[8];
  const float* Wih1f = (const float*)d_in[9];
  const float* Whh1f = (const float*)d_in[10];
  const float* bih1f = (const float*)d_in[11];
  const float* bhh1f = (const float*)d_in[12];
  const float* Wih1b = (const float*)d_in[13];
  const float* Whh1b = (const float*)d_in[14];
  const float* bih1b = (const float*)d_in[15];
  const float* bhh1b = (const float*)d_in[16];
  const float* fcw   = (const float*)d_in[17];
  const float* fcb   = (const float*)d_in[18];
  float* out = (float*)d_out;

  int slices = (int)(ws_size / (size_t)(H0_SLICE * 2));
  int grid = slices < 1 ? 1 : (slices > MAXGRID ? MAXGRID : slices);
  if (grid > NGRP) grid = NGRP;

  lstm_fc_kernel<<<dim3(grid), dim3(NTHR), 0, stream>>>(x,
      Wih0f, Whh0f, bih0f, bhh0f, Wih0b, Whh0b, bih0b, bhh0b,
      Wih1f, Whh1f, bih1f, bhh1f, Wih1b, Whh1b, bih1b, bhh1b,
      fcw, fcb, out, (_Float16*)d_ws);
}

// Round 22
// 946.505 us; speedup vs baseline: 1.2302x; 1.2302x over previous
//
#include <hip/hip_runtime.h>

typedef _Float16 half8 __attribute__((ext_vector_type(8)));
typedef float f32x4 __attribute__((ext_vector_type(4)));

#define TT 48
#define BT 32
#define NSEQ 16384
#define NGRP (NSEQ / BT)           // 512 groups
#define NTHR 512
#define MAXGRID 512
#define H0_SLICE (TT * BT * 136)   // f16 elems per block ws slice (417792 B)

// h0w layout: [t][d][b][j], stride per t = 4352 f16
struct __align__(16) Smem {
  float gates[272 * 33];        // 35904 B  [gate][batch(+pad)]
  _Float16 A[32 * 232];         // 14848 B  A panel (L0 view: [32][136])
  union {
    _Float16 bx[7 * 64 * 8];    //  7168 B  LDS B-fragments for tile 16 (during passes)
    float ysc[160];             //  FC combine scratch (after passes)
  } u;
  float fcwt[2][340];           //  2720 B  staged fcw slice, double-buffered (L1 only)
  // Occupancy shaper: push static LDS past 80 KB so only ONE block fits per CU.
  // The compiler derives its VGPR budget from LDS-limited occupancy (r21: 1024thr
  // + 60.9KB -> 64 VGPR; 512thr + <=80KB -> 128 VGPR). At 1 block/CU the budget
  // becomes 256 and the ~155-reg demand fits without spilling to scratch.
  float ldspad[6144];           // 24576 B  (never accessed)
};                              // 85216 B static LDS -> 1 block/CU by LDS

__device__ __forceinline__ float fast_rcp(float v) { return __builtin_amdgcn_rcpf(v); }
__device__ __forceinline__ float sigm(float v)  { return fast_rcp(1.f + __expf(-v)); }
__device__ __forceinline__ float tanh_s(float v){ return 1.f - 2.f * fast_rcp(1.f + __expf(2.f * v)); }

// One (layer, dir) recurrence over 32 sequences, all 8 waves.
// Wave w owns reg B-tiles {2w, 2w+1}; tile 16 via LDS bx: wave 0 lo-half, wave 1 hi-half.
template <int LAYER>
__device__ __forceinline__ void pass_lstm(Smem& s, const int d,
    const float* __restrict__ Wih, const float* __restrict__ Whh,
    const float* __restrict__ bih, const float* __restrict__ bhh,
    const float* __restrict__ xg,  const float* __restrict__ fcw,
    _Float16* __restrict__ h0w, float (&yk)[5])
{
  constexpr int AW    = LAYER ? 232 : 136;  // A row stride (f16)
  constexpr int KS    = LAYER ? 7 : 4;      // K chunks of 32 (224 / 128)
  constexpr int INW   = LAYER ? 136 : 34;   // non-recurrent width
  constexpr int BIASC = INW + 68;           // bias-one column (204 / 102)
  constexpr int HOFF  = LAYER ? 136 : 34;   // h slot base in A row

  const int tid = threadIdx.x;
  const int ln = tid & 63, wid = tid >> 6;
  const int lr = ln & 15, lq = ln >> 4;

  float* gates = s.gates;
  _Float16* A  = s.A;

  // ---- reg B fragments: 2 tiles per wave ----
  half8 Bf[2][KS];
  #pragma unroll
  for (int i = 0; i < 2; ++i) {
    const int g = (wid * 2 + i) * 16 + lr;
    #pragma unroll
    for (int kk = 0; kk < KS; ++kk) {
      half8 v;
      #pragma unroll
      for (int j = 0; j < 8; ++j) {
        const int k = kk * 32 + lq * 8 + j;
        float wv = 0.f;
        if (k < INW) wv = Wih[g * INW + k];
        else if (k < BIASC) wv = Whh[g * 68 + (k - INW)];
        else if (k == BIASC) wv = bih[g] + bhh[g];
        v[j] = (_Float16)wv;
      }
      Bf[i][kk] = v;
    }
  }
  // ---- LDS B fragments for tile 16 ----
  if (tid < KS * 64) {
    const int kk = tid >> 6, l2 = tid & 63;
    const int g = 256 + (l2 & 15);
    half8 v;
    #pragma unroll
    for (int j = 0; j < 8; ++j) {
      const int k = kk * 32 + ((l2 >> 4) & 3) * 8 + j;
      float wv = 0.f;
      if (k < INW) wv = Wih[g * INW + k];
      else if (k < BIASC) wv = Whh[g * 68 + (k - INW)];
      else if (k == BIASC) wv = bih[g] + bhh[g];
      v[j] = (_Float16)wv;
    }
    *(half8*)&s.u.bx[tid * 8] = v;
  }

  float cst[5];
  #pragma unroll
  for (int q = 0; q < 5; ++q) cst[q] = 0.f;

  // ---- staging offsets (t-independent); 1088 tasks = 2*512 + 64 extras ----
  int sgo0, sao0, sgo1, sao1, sgo2, sao2;
  if constexpr (LAYER == 0) {
    { const int b = tid / 34, i = tid % 34;
      sgo0 = b * (TT * 34) + i;  sao0 = b * 136 + i; }
    { const int t1 = tid + 512, b = t1 / 34, i = t1 % 34;
      sgo1 = b * (TT * 34) + i;  sao1 = b * 136 + i; }
    { const int t2 = (tid < 64) ? (tid + 1024) : 1024, b = t2 / 34, i = t2 % 34;
      sgo2 = b * (TT * 34) + i;  sao2 = b * 136 + i; }
  } else {
    { const int dd = tid / 544, r = tid % 544, b = r / 17, c = r % 17;
      sgo0 = dd * 2176 + b * 68 + c * 4;  sao0 = b * 232 + dd * 68 + c * 4; }
    { const int t1 = tid + 512, dd = t1 / 544, r = t1 % 544, b = r / 17, c = r % 17;
      sgo1 = dd * 2176 + b * 68 + c * 4;  sao1 = b * 232 + dd * 68 + c * 4; }
    { const int t2 = (tid < 64) ? (tid + 1024) : 1024, dd = t2 / 544, r = t2 % 544,
        b = r / 17, c = r % 17;
      sgo2 = dd * 2176 + b * 68 + c * 4;  sao2 = b * 232 + dd * 68 + c * 4; }
  }
  int fk2 = 0, fj = 0;
  if constexpr (LAYER) { if (tid < 340) { fk2 = tid / 68; fj = tid % 68; } }

  // ---- prologue: zero A (928 uint4), bias col, stage step 0 ----
  {
    const uint4 zz = {0, 0, 0, 0};
    ((uint4*)A)[tid] = zz;
    if (tid < 416) ((uint4*)A)[512 + tid] = zz;
  }
  __syncthreads();
  if (tid < 32) A[tid * AW + BIASC] = (_Float16)1.f;
  const int t0 = d ? (TT - 1) : 0;
  if constexpr (LAYER == 0) {
    A[sao0] = (_Float16)xg[sgo0 + t0 * 34];
    A[sao1] = (_Float16)xg[sgo1 + t0 * 34];
    if (tid < 64) A[sao2] = (_Float16)xg[sgo2 + t0 * 34];
  } else {
    *(uint2*)&A[sao0] = *(const uint2*)&h0w[sgo0 + t0 * 4352];
    *(uint2*)&A[sao1] = *(const uint2*)&h0w[sgo1 + t0 * 4352];
    if (tid < 64) *(uint2*)&A[sao2] = *(const uint2*)&h0w[sgo2 + t0 * 4352];
    if (tid < 340) s.fcwt[0][tid] = fcw[fk2 * 6528 + t0 * 136 + d * 68 + fj];
  }
  __syncthreads();

  #pragma unroll 1
  for (int st = 0; st < TT; ++st) {
    const int t  = d ? (TT - 1 - st) : st;
    const int tn = d ? (t - 1) : (t + 1);

    // ---- prefetch next step's staging into registers ----
    float xp0 = 0.f, xp1 = 0.f, xp2 = 0.f, fwp = 0.f;
    uint2 hp0 = {0, 0}, hp1 = {0, 0}, hp2 = {0, 0};
    if (st < TT - 1) {
      if constexpr (LAYER == 0) {
        xp0 = xg[sgo0 + tn * 34];
        xp1 = xg[sgo1 + tn * 34];
        if (tid < 64) xp2 = xg[sgo2 + tn * 34];
      } else {
        hp0 = *(const uint2*)&h0w[sgo0 + tn * 4352];
        hp1 = *(const uint2*)&h0w[sgo1 + tn * 4352];
        if (tid < 64) hp2 = *(const uint2*)&h0w[sgo2 + tn * 4352];
        if (tid < 340) fwp = fcw[fk2 * 6528 + tn * 136 + d * 68 + fj];
      }
    }

    // ---- MFMA: gates(32x272) = A(32xK).B(Kx272); concurrent lo/hi halves ----
    f32x4 aL0 = {0.f,0.f,0.f,0.f}, aH0 = {0.f,0.f,0.f,0.f};
    f32x4 aL1 = {0.f,0.f,0.f,0.f}, aH1 = {0.f,0.f,0.f,0.f};
    f32x4 a2  = {0.f,0.f,0.f,0.f};   // tile 16: wave 0 -> lo half, wave 1 -> hi half
    #pragma unroll
    for (int kk = 0; kk < KS; ++kk) {
      const half8 alo = *(const half8*)&A[lr * AW + kk * 32 + lq * 8];
      const half8 ahi = *(const half8*)&A[(lr + 16) * AW + kk * 32 + lq * 8];
      aL0 = __builtin_amdgcn_mfma_f32_16x16x32_f16(alo, Bf[0][kk], aL0, 0, 0, 0);
      aH0 = __builtin_amdgcn_mfma_f32_16x16x32_f16(ahi, Bf[0][kk], aH0, 0, 0, 0);
      aL1 = __builtin_amdgcn_mfma_f32_16x16x32_f16(alo, Bf[1][kk], aL1, 0, 0, 0);
      aH1 = __builtin_amdgcn_mfma_f32_16x16x32_f16(ahi, Bf[1][kk], aH1, 0, 0, 0);
      if (wid < 2) {
        const half8 bb = *(const half8*)&s.u.bx[(kk * 64 + ln) * 8];
        const half8 av = (wid == 0) ? alo : ahi;
        a2 = __builtin_amdgcn_mfma_f32_16x16x32_f16(av, bb, a2, 0, 0, 0);
      }
    }
    // C/D: col = lr (gate within tile), row = lq*4+r (batch; +16 for hi tile)
    {
      const int g0 = (wid * 2) * 16 + lr;
      #pragma unroll
      for (int r = 0; r < 4; ++r) {
        gates[g0 * 33 + lq * 4 + r]              = aL0[r];
        gates[g0 * 33 + 16 + lq * 4 + r]         = aH0[r];
        gates[(g0 + 16) * 33 + lq * 4 + r]       = aL1[r];
        gates[(g0 + 16) * 33 + 16 + lq * 4 + r]  = aH1[r];
      }
      if (wid < 2) {
        #pragma unroll
        for (int r = 0; r < 4; ++r)
          gates[(256 + lr) * 33 + 16 * wid + lq * 4 + r] = a2[r];
      }
    }
    __syncthreads();

    // ---- elementwise cell update: b-uniform ownership ----
    {
      const int b = tid >> 4, jb = tid & 15;
      #pragma unroll
      for (int q = 0; q < 5; ++q) {
        if (q < 4 || jb < 4) {
          const int j = (q < 4) ? (jb + 16 * q) : (64 + jb);
          const int gq = j * 33 + b;
          const float gi = gates[gq];
          const float gf = gates[gq + 2244];    // (68+j)*33+b
          const float gg = gates[gq + 4488];
          const float go = gates[gq + 6732];
          const float ii = sigm(gi), ff = sigm(gf), g2 = tanh_s(gg), oo = sigm(go);
          const float cc = ff * cst[q] + ii * g2;
          cst[q] = cc;
          const float h = oo * tanh_s(cc);
          const _Float16 h16 = (_Float16)h;
          A[b * AW + HOFF + j] = h16;
          if constexpr (LAYER == 0) {
            h0w[t * 4352 + d * 2176 + b * 68 + j] = h16;
          } else {
            #pragma unroll
            for (int k = 0; k < 5; ++k) yk[k] += h * s.fcwt[st & 1][k * 68 + j];
          }
        }
      }
    }
    // ---- staging writes for next step ----
    if (st < TT - 1) {
      if constexpr (LAYER == 0) {
        A[sao0] = (_Float16)xp0;
        A[sao1] = (_Float16)xp1;
        if (tid < 64) A[sao2] = (_Float16)xp2;
      } else {
        *(uint2*)&A[sao0] = hp0;
        *(uint2*)&A[sao1] = hp1;
        if (tid < 64) *(uint2*)&A[sao2] = hp2;
        if (tid < 340) s.fcwt[(st + 1) & 1][tid] = fwp;
      }
    }
    __syncthreads();
  }
}

__global__ __attribute__((amdgpu_flat_work_group_size(NTHR, NTHR)))
void lstm_fc_kernel(
    const float* __restrict__ x,
    const float* __restrict__ Wih0f, const float* __restrict__ Whh0f,
    const float* __restrict__ bih0f, const float* __restrict__ bhh0f,
    const float* __restrict__ Wih0b, const float* __restrict__ Whh0b,
    const float* __restrict__ bih0b, const float* __restrict__ bhh0b,
    const float* __restrict__ Wih1f, const float* __restrict__ Whh1f,
    const float* __restrict__ bih1f, const float* __restrict__ bhh1f,
    const float* __restrict__ Wih1b, const float* __restrict__ Whh1b,
    const float* __restrict__ bih1b, const float* __restrict__ bhh1b,
    const float* __restrict__ fcw, const float* __restrict__ fcb,
    float* __restrict__ out, _Float16* __restrict__ ws)
{
  __shared__ Smem s;
  const int tid = threadIdx.x;
  _Float16* h0w = ws + (size_t)blockIdx.x * H0_SLICE;

  for (int grp = blockIdx.x; grp < NGRP; grp += gridDim.x) {
    const float* xg = x + (size_t)grp * (BT * TT * 34);
    float yk[5] = {0.f, 0.f, 0.f, 0.f, 0.f};

    pass_lstm<0>(s, 0, Wih0f, Whh0f, bih0f, bhh0f, xg, nullptr, h0w, yk);
    pass_lstm<0>(s, 1, Wih0b, Whh0b, bih0b, bhh0b, xg, nullptr, h0w, yk);
    pass_lstm<1>(s, 0, Wih1f, Whh1f, bih1f, bhh1f, nullptr, fcw, h0w, yk);
    pass_lstm<1>(s, 1, Wih1b, Whh1b, bih1b, bhh1b, nullptr, fcw, h0w, yk);

    // ---- FC epilogue: butterfly over the 16 threads sharing b, then combine ----
    #pragma unroll
    for (int m = 1; m < 16; m <<= 1) {
      #pragma unroll
      for (int k = 0; k < 5; ++k) yk[k] += __shfl_xor(yk[k], m, 64);
    }
    __syncthreads();   // all passes done before overwriting bx-union with ysc
    if ((tid & 15) == 0) {
      #pragma unroll
      for (int k = 0; k < 5; ++k) s.u.ysc[(tid >> 4) * 5 + k] = yk[k];
    }
    __syncthreads();
    if (tid < BT * 5) {
      const int k = tid % 5;
      out[(size_t)(grp * BT) * 5 + tid] = s.u.ysc[tid] + fcb[k];
    }
    __syncthreads();
  }
}

extern "C" void kernel_launch(void* const* d_in, const int* in_sizes, int n_in,
                              void* d_out, int out_size, void* d_ws, size_t ws_size,
                              hipStream_t stream) {
  (void)in_sizes; (void)n_in; (void)out_size;
  static_assert(sizeof(Smem) > 80 * 1024, "pad must force 1 block/CU");
  static_assert(sizeof(Smem) <= 120 * 1024, "LDS budget");

  const float* x     = (const float*)d_in[0];
  const float* Wih0f = (const float*)d_in[1];
  const float* Whh0f = (const float*)d_in[2];
  const float* bih0f = (const float*)d_in[3];
  const float* bhh0f = (const float*)d_in[4];
  const float* Wih0b = (const float*)d_in[5];
  const float* Whh0b = (const float*)d_in[6];
  const float* bih0b = (const float*)d_in[7];
  const float* bhh0b = (const float*)d_in[8];
  const float* Wih1f = (const float*)d_in[9];
  const float* Whh1f = (const float*)d_in[10];
  const float* bih1f = (const float*)d_in[11];
  const float* bhh1f = (const float*)d_in[12];
  const float* Wih1b = (const float*)d_in[13];
  const float* Whh1b = (const float*)d_in[14];
  const float* bih1b = (const float*)d_in[15];
  const float* bhh1b = (const float*)d_in[16];
  const float* fcw   = (const float*)d_in[17];
  const float* fcb   = (const float*)d_in[18];
  float* out = (float*)d_out;

  int slices = (int)(ws_size / (size_t)(H0_SLICE * 2));
  int grid = slices < 1 ? 1 : (slices > MAXGRID ? MAXGRID : slices);
  if (grid > NGRP) grid = NGRP;

  lstm_fc_kernel<<<dim3(grid), dim3(NTHR), 0, stream>>>(x,
      Wih0f, Whh0f, bih0f, bhh0f, Wih0b, Whh0b, bih0b, bhh0b,
      Wih1f, Whh1f, bih1f, bhh1f, Wih1b, Whh1b, bih1b, bhh1b,
      fcw, fcb, out, (_Float16*)d_ws);
}

// Round 23
// 923.239 us; speedup vs baseline: 1.2612x; 1.0252x over previous
//
#include <hip/hip_runtime.h>

typedef _Float16 half8 __attribute__((ext_vector_type(8)));
typedef float f32x4 __attribute__((ext_vector_type(4)));

#define TT 48
#define BT 32
#define NSEQ 16384
#define NGRP (NSEQ / BT)           // 512 groups
#define NTHR 512
#define MAXGRID 512
#define H0_SLICE (TT * BT * 136)   // f16 elems per block ws slice (417792 B)
#define GSTR 276                   // gates row stride (b-major); 276%32=20 -> 2-way banks

// h0w layout: [t][d][b][j], stride per t = 4352 f16
struct __align__(16) Smem {
  float gates[32 * GSTR];       // 35328 B  [batch][gate(+pad)] b-major, stride 276
  _Float16 A[32 * 232];         // 14848 B  A panel (L0 view: [32][136])
  union {
    _Float16 bx[7 * 64 * 8];    //  7168 B  LDS B-fragments for tile 16 (during passes)
    float ysc[160];             //  FC combine scratch (after passes)
  } u;
  float fcwt[2][340];           //  2720 B  staged fcw slice, double-buffered (L1 only)
};                              // 60064 B static LDS

__device__ __forceinline__ float fast_rcp(float v) { return __builtin_amdgcn_rcpf(v); }
__device__ __forceinline__ float sigm(float v)  { return fast_rcp(1.f + __expf(-v)); }
__device__ __forceinline__ float tanh_s(float v){ return 1.f - 2.f * fast_rcp(1.f + __expf(2.f * v)); }

// One (layer, dir) recurrence over 32 sequences, all 8 waves.
// Wave w owns reg B-tiles {2w, 2w+1}; tile 16 via LDS bx: wave 0 lo-half, wave 1 hi-half.
template <int LAYER>
__device__ __forceinline__ void pass_lstm(Smem& s, const int d,
    const float* __restrict__ Wih, const float* __restrict__ Whh,
    const float* __restrict__ bih, const float* __restrict__ bhh,
    const float* __restrict__ xg,  const float* __restrict__ fcw,
    _Float16* __restrict__ h0w, float (&yk)[5])
{
  constexpr int AW    = LAYER ? 232 : 136;  // A row stride (f16)
  constexpr int KS    = LAYER ? 7 : 4;      // K chunks of 32 (224 / 128)
  constexpr int INW   = LAYER ? 136 : 34;   // non-recurrent width
  constexpr int BIASC = INW + 68;           // bias-one column (204 / 102)
  constexpr int HOFF  = LAYER ? 136 : 34;   // h slot base in A row

  const int tid = threadIdx.x;
  const int ln = tid & 63, wid = tid >> 6;
  const int lr = ln & 15, lq = ln >> 4;

  float* gates = s.gates;
  _Float16* A  = s.A;

  // ---- reg B fragments: 2 tiles per wave ----
  half8 Bf[2][KS];
  #pragma unroll
  for (int i = 0; i < 2; ++i) {
    const int g = (wid * 2 + i) * 16 + lr;
    #pragma unroll
    for (int kk = 0; kk < KS; ++kk) {
      half8 v;
      #pragma unroll
      for (int j = 0; j < 8; ++j) {
        const int k = kk * 32 + lq * 8 + j;
        float wv = 0.f;
        if (k < INW) wv = Wih[g * INW + k];
        else if (k < BIASC) wv = Whh[g * 68 + (k - INW)];
        else if (k == BIASC) wv = bih[g] + bhh[g];
        v[j] = (_Float16)wv;
      }
      Bf[i][kk] = v;
    }
  }
  // ---- LDS B fragments for tile 16 ----
  if (tid < KS * 64) {
    const int kk = tid >> 6, l2 = tid & 63;
    const int g = 256 + (l2 & 15);
    half8 v;
    #pragma unroll
    for (int j = 0; j < 8; ++j) {
      const int k = kk * 32 + ((l2 >> 4) & 3) * 8 + j;
      float wv = 0.f;
      if (k < INW) wv = Wih[g * INW + k];
      else if (k < BIASC) wv = Whh[g * 68 + (k - INW)];
      else if (k == BIASC) wv = bih[g] + bhh[g];
      v[j] = (_Float16)wv;
    }
    *(half8*)&s.u.bx[tid * 8] = v;
  }

  float cst[5];
  #pragma unroll
  for (int q = 0; q < 5; ++q) cst[q] = 0.f;

  // ---- staging offsets (t-independent); 1088 tasks = 2*512 + 64 extras ----
  int sgo0, sao0, sgo1, sao1, sgo2, sao2;
  if constexpr (LAYER == 0) {
    { const int b = tid / 34, i = tid % 34;
      sgo0 = b * (TT * 34) + i;  sao0 = b * 136 + i; }
    { const int t1 = tid + 512, b = t1 / 34, i = t1 % 34;
      sgo1 = b * (TT * 34) + i;  sao1 = b * 136 + i; }
    { const int t2 = (tid < 64) ? (tid + 1024) : 1024, b = t2 / 34, i = t2 % 34;
      sgo2 = b * (TT * 34) + i;  sao2 = b * 136 + i; }
  } else {
    { const int dd = tid / 544, r = tid % 544, b = r / 17, c = r % 17;
      sgo0 = dd * 2176 + b * 68 + c * 4;  sao0 = b * 232 + dd * 68 + c * 4; }
    { const int t1 = tid + 512, dd = t1 / 544, r = t1 % 544, b = r / 17, c = r % 17;
      sgo1 = dd * 2176 + b * 68 + c * 4;  sao1 = b * 232 + dd * 68 + c * 4; }
    { const int t2 = (tid < 64) ? (tid + 1024) : 1024, dd = t2 / 544, r = t2 % 544,
        b = r / 17, c = r % 17;
      sgo2 = dd * 2176 + b * 68 + c * 4;  sao2 = b * 232 + dd * 68 + c * 4; }
  }
  int fk2 = 0, fj = 0;
  if constexpr (LAYER) { if (tid < 340) { fk2 = tid / 68; fj = tid % 68; } }

  // ---- prologue: zero A (928 uint4), bias col, stage step 0 ----
  {
    const uint4 zz = {0, 0, 0, 0};
    ((uint4*)A)[tid] = zz;
    if (tid < 416) ((uint4*)A)[512 + tid] = zz;
  }
  __syncthreads();
  if (tid < 32) A[tid * AW + BIASC] = (_Float16)1.f;
  const int t0 = d ? (TT - 1) : 0;
  if constexpr (LAYER == 0) {
    A[sao0] = (_Float16)xg[sgo0 + t0 * 34];
    A[sao1] = (_Float16)xg[sgo1 + t0 * 34];
    if (tid < 64) A[sao2] = (_Float16)xg[sgo2 + t0 * 34];
  } else {
    *(uint2*)&A[sao0] = *(const uint2*)&h0w[sgo0 + t0 * 4352];
    *(uint2*)&A[sao1] = *(const uint2*)&h0w[sgo1 + t0 * 4352];
    if (tid < 64) *(uint2*)&A[sao2] = *(const uint2*)&h0w[sgo2 + t0 * 4352];
    if (tid < 340) s.fcwt[0][tid] = fcw[fk2 * 6528 + t0 * 136 + d * 68 + fj];
  }
  __syncthreads();

  #pragma unroll 1
  for (int st = 0; st < TT; ++st) {
    const int t  = d ? (TT - 1 - st) : st;
    const int tn = d ? (t - 1) : (t + 1);

    // ---- prefetch next step's staging into registers ----
    float xp0 = 0.f, xp1 = 0.f, xp2 = 0.f, fwp = 0.f;
    uint2 hp0 = {0, 0}, hp1 = {0, 0}, hp2 = {0, 0};
    if (st < TT - 1) {
      if constexpr (LAYER == 0) {
        xp0 = xg[sgo0 + tn * 34];
        xp1 = xg[sgo1 + tn * 34];
        if (tid < 64) xp2 = xg[sgo2 + tn * 34];
      } else {
        hp0 = *(const uint2*)&h0w[sgo0 + tn * 4352];
        hp1 = *(const uint2*)&h0w[sgo1 + tn * 4352];
        if (tid < 64) hp2 = *(const uint2*)&h0w[sgo2 + tn * 4352];
        if (tid < 340) fwp = fcw[fk2 * 6528 + tn * 136 + d * 68 + fj];
      }
    }

    // ---- MFMA: gates(32x272) = A(32xK).B(Kx272); concurrent lo/hi halves ----
    f32x4 aL0 = {0.f,0.f,0.f,0.f}, aH0 = {0.f,0.f,0.f,0.f};
    f32x4 aL1 = {0.f,0.f,0.f,0.f}, aH1 = {0.f,0.f,0.f,0.f};
    f32x4 a2  = {0.f,0.f,0.f,0.f};   // tile 16: wave 0 -> lo half, wave 1 -> hi half
    #pragma unroll
    for (int kk = 0; kk < KS; ++kk) {
      const half8 alo = *(const half8*)&A[lr * AW + kk * 32 + lq * 8];
      const half8 ahi = *(const half8*)&A[(lr + 16) * AW + kk * 32 + lq * 8];
      aL0 = __builtin_amdgcn_mfma_f32_16x16x32_f16(alo, Bf[0][kk], aL0, 0, 0, 0);
      aH0 = __builtin_amdgcn_mfma_f32_16x16x32_f16(ahi, Bf[0][kk], aH0, 0, 0, 0);
      aL1 = __builtin_amdgcn_mfma_f32_16x16x32_f16(alo, Bf[1][kk], aL1, 0, 0, 0);
      aH1 = __builtin_amdgcn_mfma_f32_16x16x32_f16(ahi, Bf[1][kk], aH1, 0, 0, 0);
      if (wid < 2) {
        const half8 bb = *(const half8*)&s.u.bx[(kk * 64 + ln) * 8];
        const half8 av = (wid == 0) ? alo : ahi;
        a2 = __builtin_amdgcn_mfma_f32_16x16x32_f16(av, bb, a2, 0, 0, 0);
      }
    }
    // C/D -> b-major gates: row = batch = lq*4+r (+16 hi), col = gate
    {
      const int g0 = (wid * 2) * 16 + lr;
      #pragma unroll
      for (int r = 0; r < 4; ++r) {
        gates[(lq * 4 + r) * GSTR + g0]            = aL0[r];
        gates[(16 + lq * 4 + r) * GSTR + g0]       = aH0[r];
        gates[(lq * 4 + r) * GSTR + g0 + 16]       = aL1[r];
        gates[(16 + lq * 4 + r) * GSTR + g0 + 16]  = aH1[r];
      }
      if (wid < 2) {
        #pragma unroll
        for (int r = 0; r < 4; ++r)
          gates[(16 * wid + lq * 4 + r) * GSTR + 256 + lr] = a2[r];
      }
    }
    __syncthreads();

    // ---- elementwise cell update: b-uniform ownership (b-major gates reads) ----
    {
      const int b = tid >> 4, jb = tid & 15;
      const int gb = b * GSTR;
      #pragma unroll
      for (int q = 0; q < 5; ++q) {
        if (q < 4 || jb < 4) {
          const int j = (q < 4) ? (jb + 16 * q) : (64 + jb);
          const float gi = gates[gb + j];
          const float gf = gates[gb + 68 + j];
          const float gg = gates[gb + 136 + j];
          const float go = gates[gb + 204 + j];
          const float ii = sigm(gi), ff = sigm(gf), g2 = tanh_s(gg), oo = sigm(go);
          const float cc = ff * cst[q] + ii * g2;
          cst[q] = cc;
          const float h = oo * tanh_s(cc);
          const _Float16 h16 = (_Float16)h;
          A[b * AW + HOFF + j] = h16;
          if constexpr (LAYER == 0) {
            h0w[t * 4352 + d * 2176 + b * 68 + j] = h16;
          } else {
            #pragma unroll
            for (int k = 0; k < 5; ++k) yk[k] += h * s.fcwt[st & 1][k * 68 + j];
          }
        }
      }
    }
    // ---- staging writes for next step ----
    if (st < TT - 1) {
      if constexpr (LAYER == 0) {
        A[sao0] = (_Float16)xp0;
        A[sao1] = (_Float16)xp1;
        if (tid < 64) A[sao2] = (_Float16)xp2;
      } else {
        *(uint2*)&A[sao0] = hp0;
        *(uint2*)&A[sao1] = hp1;
        if (tid < 64) *(uint2*)&A[sao2] = hp2;
        if (tid < 340) s.fcwt[(st + 1) & 1][tid] = fwp;
      }
    }
    __syncthreads();
  }
}

__global__ __attribute__((amdgpu_flat_work_group_size(NTHR, NTHR)))
void lstm_fc_kernel(
    const float* __restrict__ x,
    const float* __restrict__ Wih0f, const float* __restrict__ Whh0f,
    const float* __restrict__ bih0f, const float* __restrict__ bhh0f,
    const float* __restrict__ Wih0b, const float* __restrict__ Whh0b,
    const float* __restrict__ bih0b, const float* __restrict__ bhh0b,
    const float* __restrict__ Wih1f, const float* __restrict__ Whh1f,
    const float* __restrict__ bih1f, const float* __restrict__ bhh1f,
    const float* __restrict__ Wih1b, const float* __restrict__ Whh1b,
    const float* __restrict__ bih1b, const float* __restrict__ bhh1b,
    const float* __restrict__ fcw, const float* __restrict__ fcb,
    float* __restrict__ out, _Float16* __restrict__ ws)
{
  __shared__ Smem s;
  const int tid = threadIdx.x;
  _Float16* h0w = ws + (size_t)blockIdx.x * H0_SLICE;

  for (int grp = blockIdx.x; grp < NGRP; grp += gridDim.x) {
    const float* xg = x + (size_t)grp * (BT * TT * 34);
    float yk[5] = {0.f, 0.f, 0.f, 0.f, 0.f};

    pass_lstm<0>(s, 0, Wih0f, Whh0f, bih0f, bhh0f, xg, nullptr, h0w, yk);
    pass_lstm<0>(s, 1, Wih0b, Whh0b, bih0b, bhh0b, xg, nullptr, h0w, yk);
    pass_lstm<1>(s, 0, Wih1f, Whh1f, bih1f, bhh1f, nullptr, fcw, h0w, yk);
    pass_lstm<1>(s, 1, Wih1b, Whh1b, bih1b, bhh1b, nullptr, fcw, h0w, yk);

    // ---- FC epilogue: butterfly over the 16 threads sharing b, then combine ----
    #pragma unroll
    for (int m = 1; m < 16; m <<= 1) {
      #pragma unroll
      for (int k = 0; k < 5; ++k) yk[k] += __shfl_xor(yk[k], m, 64);
    }
    __syncthreads();   // all passes done before overwriting bx-union with ysc
    if ((tid & 15) == 0) {
      #pragma unroll
      for (int k = 0; k < 5; ++k) s.u.ysc[(tid >> 4) * 5 + k] = yk[k];
    }
    __syncthreads();
    if (tid < BT * 5) {
      const int k = tid % 5;
      out[(size_t)(grp * BT) * 5 + tid] = s.u.ysc[tid] + fcb[k];
    }
    __syncthreads();
  }
}

extern "C" void kernel_launch(void* const* d_in, const int* in_sizes, int n_in,
                              void* d_out, int out_size, void* d_ws, size_t ws_size,
                              hipStream_t stream) {
  (void)in_sizes; (void)n_in; (void)out_size;
  static_assert(sizeof(Smem) <= 64 * 1024, "LDS budget");

  const float* x     = (const float*)d_in[0];
  const float* Wih0f = (const float*)d_in[1];
  const float* Whh0f = (const float*)d_in[2];
  const float* bih0f = (const float*)d_in[3];
  const float* bhh0f = (const float*)d_in[4];
  const float* Wih0b = (const float*)d_in[5];
  const float* Whh0b = (const float*)d_in[6];
  const float* bih0b = (const float*)d_in[7];
  const float* bhh0b = (const float*)d_in[8];
  const float* Wih1f = (const float*)d_in[9];
  const float* Whh1f = (const float*)d_in[10];
  const float* bih1f = (const float*)d_in[11];
  const float* bhh1f = (const float*)d_in[12];
  const float* Wih1b = (const float*)d_in[13];
  const float* Whh1b = (const float*)d_in[14];
  const float* bih1b = (const float*)d_in[15];
  const float* bhh1b = (const float*)d_in[16];
  const float* fcw   = (const float*)d_in[17];
  const float* fcb   = (const float*)d_in[18];
  float* out = (float*)d_out;

  int slices = (int)(ws_size / (size_t)(H0_SLICE * 2));
  int grid = slices < 1 ? 1 : (slices > MAXGRID ? MAXGRID : slices);
  if (grid > NGRP) grid = NGRP;

  lstm_fc_kernel<<<dim3(grid), dim3(NTHR), 0, stream>>>(x,
      Wih0f, Whh0f, bih0f, bhh0f, Wih0b, Whh0b, bih0b, bhh0b,
      Wih1f, Whh1f, bih1f, bhh1f, Wih1b, Whh1b, bih1b, bhh1b,
      fcw, fcb, out, (_Float16*)d_ws);
}

// Round 24
// 785.731 us; speedup vs baseline: 1.4819x; 1.1750x over previous
//
#include <hip/hip_runtime.h>

typedef _Float16 half8 __attribute__((ext_vector_type(8)));
typedef float f32x4 __attribute__((ext_vector_type(4)));

#define TT 48
#define BT 32
#define NSEQ 16384
#define NGRP (NSEQ / BT)            // 512 groups
#define NTHR 512
#define GSTR 276                    // gates row stride (b-major); 276%32=20 -> ~2-way banks
#define SLICE_E (TT * BT * 136)     // 208896 f16 elems per group h0 slice
#define SLICE_B (SLICE_E * 2)       // 417792 bytes
#define YPART_FLOATS (NGRP * 2 * BT * 5)   // 163840 floats = 655360 B

__device__ __forceinline__ float fast_rcp(float v) { return __builtin_amdgcn_rcpf(v); }
__device__ __forceinline__ float sigm(float v)  { return fast_rcp(1.f + __expf(-v)); }
__device__ __forceinline__ float tanh_s(float v){ return 1.f - 2.f * fast_rcp(1.f + __expf(2.f * v)); }

//==================== kernel A: layer-0, one (group,dir) per block ====================
struct __align__(16) SmemL0 {
  float gates[32 * GSTR];       // 35328 B
  _Float16 A[32 * 136];         //  8704 B  [x(34) | h(68) | pad | bias@102 ...]
  _Float16 bx[4 * 64 * 8];      //  4096 B  tile-16 B fragments
};                              // 48128 B -> 2 blocks/CU if regs fit

__global__ __attribute__((amdgpu_flat_work_group_size(NTHR, NTHR)))
void l0_pass(const float* __restrict__ x,
    const float* __restrict__ WihF, const float* __restrict__ WhhF,
    const float* __restrict__ bihF, const float* __restrict__ bhhF,
    const float* __restrict__ WihB, const float* __restrict__ WhhB,
    const float* __restrict__ bihB, const float* __restrict__ bhhB,
    _Float16* __restrict__ ws, int c0)
{
  __shared__ SmemL0 s;
  const int tid = threadIdx.x;
  const int ln = tid & 63, wid = tid >> 6;
  const int lr = ln & 15, lq = ln >> 4;
  const int g_loc = blockIdx.x >> 1, d = blockIdx.x & 1;
  _Float16* h0w = ws + (size_t)g_loc * SLICE_E;
  const float* xg = x + (size_t)(c0 + g_loc) * (BT * TT * 34);
  const float* Wih = d ? WihB : WihF;
  const float* Whh = d ? WhhB : WhhF;
  const float* bih = d ? bihB : bihF;
  const float* bhh = d ? bhhB : bhhF;

  // reg B fragments: 2 tiles/wave, K = 128 (x|h|bias)
  half8 Bf[2][4];
  #pragma unroll
  for (int i = 0; i < 2; ++i) {
    const int g = (wid * 2 + i) * 16 + lr;
    #pragma unroll
    for (int kk = 0; kk < 4; ++kk) {
      half8 v;
      #pragma unroll
      for (int j = 0; j < 8; ++j) {
        const int k = kk * 32 + lq * 8 + j;
        float wv = 0.f;
        if (k < 34) wv = Wih[g * 34 + k];
        else if (k < 102) wv = Whh[g * 68 + (k - 34)];
        else if (k == 102) wv = bih[g] + bhh[g];
        v[j] = (_Float16)wv;
      }
      Bf[i][kk] = v;
    }
  }
  if (tid < 4 * 64) {
    const int kk = tid >> 6, l2 = tid & 63;
    const int g = 256 + (l2 & 15);
    half8 v;
    #pragma unroll
    for (int j = 0; j < 8; ++j) {
      const int k = kk * 32 + ((l2 >> 4) & 3) * 8 + j;
      float wv = 0.f;
      if (k < 34) wv = Wih[g * 34 + k];
      else if (k < 102) wv = Whh[g * 68 + (k - 34)];
      else if (k == 102) wv = bih[g] + bhh[g];
      v[j] = (_Float16)wv;
    }
    *(half8*)&s.bx[tid * 8] = v;
  }

  float cst[5];
  #pragma unroll
  for (int q = 0; q < 5; ++q) cst[q] = 0.f;

  // staging offsets: 1088 = 32b x 34i tasks
  int sgo0, sao0, sgo1, sao1, sgo2, sao2;
  { const int b = tid / 34, i = tid % 34;
    sgo0 = b * (TT * 34) + i;  sao0 = b * 136 + i; }
  { const int t1 = tid + 512, b = t1 / 34, i = t1 % 34;
    sgo1 = b * (TT * 34) + i;  sao1 = b * 136 + i; }
  { const int t2 = (tid < 64) ? (tid + 1024) : 1024, b = t2 / 34, i = t2 % 34;
    sgo2 = b * (TT * 34) + i;  sao2 = b * 136 + i; }

  // prologue: zero A (544 uint4), bias col, stage step 0
  {
    const uint4 zz = {0, 0, 0, 0};
    ((uint4*)s.A)[tid] = zz;
    if (tid < 32) ((uint4*)s.A)[512 + tid] = zz;
  }
  __syncthreads();
  if (tid < 32) s.A[tid * 136 + 102] = (_Float16)1.f;
  const int t0 = d ? (TT - 1) : 0;
  s.A[sao0] = (_Float16)xg[sgo0 + t0 * 34];
  s.A[sao1] = (_Float16)xg[sgo1 + t0 * 34];
  if (tid < 64) s.A[sao2] = (_Float16)xg[sgo2 + t0 * 34];
  __syncthreads();

  #pragma unroll 1
  for (int st = 0; st < TT; ++st) {
    const int t  = d ? (TT - 1 - st) : st;
    const int tn = d ? (t - 1) : (t + 1);

    float xp0 = 0.f, xp1 = 0.f, xp2 = 0.f;
    if (st < TT - 1) {
      xp0 = xg[sgo0 + tn * 34];
      xp1 = xg[sgo1 + tn * 34];
      if (tid < 64) xp2 = xg[sgo2 + tn * 34];
    }

    f32x4 aL0 = {0.f,0.f,0.f,0.f}, aH0 = {0.f,0.f,0.f,0.f};
    f32x4 aL1 = {0.f,0.f,0.f,0.f}, aH1 = {0.f,0.f,0.f,0.f};
    f32x4 a2  = {0.f,0.f,0.f,0.f};
    #pragma unroll
    for (int kk = 0; kk < 4; ++kk) {
      const half8 alo = *(const half8*)&s.A[lr * 136 + kk * 32 + lq * 8];
      const half8 ahi = *(const half8*)&s.A[(lr + 16) * 136 + kk * 32 + lq * 8];
      aL0 = __builtin_amdgcn_mfma_f32_16x16x32_f16(alo, Bf[0][kk], aL0, 0, 0, 0);
      aH0 = __builtin_amdgcn_mfma_f32_16x16x32_f16(ahi, Bf[0][kk], aH0, 0, 0, 0);
      aL1 = __builtin_amdgcn_mfma_f32_16x16x32_f16(alo, Bf[1][kk], aL1, 0, 0, 0);
      aH1 = __builtin_amdgcn_mfma_f32_16x16x32_f16(ahi, Bf[1][kk], aH1, 0, 0, 0);
      if (wid < 2) {
        const half8 bb = *(const half8*)&s.bx[(kk * 64 + ln) * 8];
        const half8 av = (wid == 0) ? alo : ahi;
        a2 = __builtin_amdgcn_mfma_f32_16x16x32_f16(av, bb, a2, 0, 0, 0);
      }
    }
    {
      const int g0 = (wid * 2) * 16 + lr;
      #pragma unroll
      for (int r = 0; r < 4; ++r) {
        s.gates[(lq * 4 + r) * GSTR + g0]            = aL0[r];
        s.gates[(16 + lq * 4 + r) * GSTR + g0]       = aH0[r];
        s.gates[(lq * 4 + r) * GSTR + g0 + 16]       = aL1[r];
        s.gates[(16 + lq * 4 + r) * GSTR + g0 + 16]  = aH1[r];
      }
      if (wid < 2) {
        #pragma unroll
        for (int r = 0; r < 4; ++r)
          s.gates[(16 * wid + lq * 4 + r) * GSTR + 256 + lr] = a2[r];
      }
    }
    __syncthreads();

    {
      const int b = tid >> 4, jb = tid & 15;
      const int gb = b * GSTR;
      #pragma unroll
      for (int q = 0; q < 5; ++q) {
        if (q < 4 || jb < 4) {
          const int j = (q < 4) ? (jb + 16 * q) : (64 + jb);
          const float gi = s.gates[gb + j];
          const float gf = s.gates[gb + 68 + j];
          const float gg = s.gates[gb + 136 + j];
          const float go = s.gates[gb + 204 + j];
          const float ii = sigm(gi), ff = sigm(gf), g2 = tanh_s(gg), oo = sigm(go);
          const float cc = ff * cst[q] + ii * g2;
          cst[q] = cc;
          const float h = oo * tanh_s(cc);
          const _Float16 h16 = (_Float16)h;
          s.A[b * 136 + 34 + j] = h16;
          h0w[t * 4352 + d * 2176 + b * 68 + j] = h16;
        }
      }
    }
    if (st < TT - 1) {
      s.A[sao0] = (_Float16)xp0;
      s.A[sao1] = (_Float16)xp1;
      if (tid < 64) s.A[sao2] = (_Float16)xp2;
    }
    __syncthreads();
  }
}

//==================== kernel B: layer-1 + FC partial, one (group,dir) per block ====================
struct __align__(16) SmemL1 {
  float gates[32 * GSTR];       // 35328 B
  _Float16 A[32 * 232];         // 14848 B  [h0(136) | h1(68) | pad | bias@204 ...]
  union {
    _Float16 bx[7 * 64 * 8];    //  7168 B
    float ysc[160];
  } u;
  float fcwt[2][340];           //  2720 B
};                              // 60064 B

__global__ __attribute__((amdgpu_flat_work_group_size(NTHR, NTHR)))
void l1_pass(
    const float* __restrict__ WihF, const float* __restrict__ WhhF,
    const float* __restrict__ bihF, const float* __restrict__ bhhF,
    const float* __restrict__ WihB, const float* __restrict__ WhhB,
    const float* __restrict__ bihB, const float* __restrict__ bhhB,
    const float* __restrict__ fcw,
    _Float16* __restrict__ ws, float* __restrict__ ypart, int c0)
{
  __shared__ SmemL1 s;
  const int tid = threadIdx.x;
  const int ln = tid & 63, wid = tid >> 6;
  const int lr = ln & 15, lq = ln >> 4;
  const int g_loc = blockIdx.x >> 1, d = blockIdx.x & 1;
  const int g = c0 + g_loc;
  _Float16* h0w = ws + (size_t)g_loc * SLICE_E;
  const float* Wih = d ? WihB : WihF;
  const float* Whh = d ? WhhB : WhhF;
  const float* bih = d ? bihB : bihF;
  const float* bhh = d ? bhhB : bhhF;

  // reg B fragments: 2 tiles/wave, K = 224 (h0|h1|bias)
  half8 Bf[2][7];
  #pragma unroll
  for (int i = 0; i < 2; ++i) {
    const int gg_ = (wid * 2 + i) * 16 + lr;
    #pragma unroll
    for (int kk = 0; kk < 7; ++kk) {
      half8 v;
      #pragma unroll
      for (int j = 0; j < 8; ++j) {
        const int k = kk * 32 + lq * 8 + j;
        float wv = 0.f;
        if (k < 136) wv = Wih[gg_ * 136 + k];
        else if (k < 204) wv = Whh[gg_ * 68 + (k - 136)];
        else if (k == 204) wv = bih[gg_] + bhh[gg_];
        v[j] = (_Float16)wv;
      }
      Bf[i][kk] = v;
    }
  }
  if (tid < 7 * 64) {
    const int kk = tid / 64, l2 = tid & 63;
    const int gg_ = 256 + (l2 & 15);
    half8 v;
    #pragma unroll
    for (int j = 0; j < 8; ++j) {
      const int k = kk * 32 + ((l2 >> 4) & 3) * 8 + j;
      float wv = 0.f;
      if (k < 136) wv = Wih[gg_ * 136 + k];
      else if (k < 204) wv = Whh[gg_ * 68 + (k - 136)];
      else if (k == 204) wv = bih[gg_] + bhh[gg_];
      v[j] = (_Float16)wv;
    }
    *(half8*)&s.u.bx[tid * 8] = v;
  }

  float cst[5], yk[5];
  #pragma unroll
  for (int q = 0; q < 5; ++q) { cst[q] = 0.f; yk[q] = 0.f; }

  // staging offsets: 1088 = 2dd x 32b x 17c (uint2 chunks of h0 row)
  int sgo0, sao0, sgo1, sao1, sgo2, sao2;
  { const int dd = tid / 544, r = tid % 544, b = r / 17, c = r % 17;
    sgo0 = dd * 2176 + b * 68 + c * 4;  sao0 = b * 232 + dd * 68 + c * 4; }
  { const int t1 = tid + 512, dd = t1 / 544, r = t1 % 544, b = r / 17, c = r % 17;
    sgo1 = dd * 2176 + b * 68 + c * 4;  sao1 = b * 232 + dd * 68 + c * 4; }
  { const int t2 = (tid < 64) ? (tid + 1024) : 1024, dd = t2 / 544, r = t2 % 544,
      b = r / 17, c = r % 17;
    sgo2 = dd * 2176 + b * 68 + c * 4;  sao2 = b * 232 + dd * 68 + c * 4; }
  int fk2 = 0, fj = 0;
  if (tid < 340) { fk2 = tid / 68; fj = tid % 68; }

  // prologue: zero A (928 uint4), bias col, stage step 0 + fcwt[0]
  {
    const uint4 zz = {0, 0, 0, 0};
    ((uint4*)s.A)[tid] = zz;
    if (tid < 416) ((uint4*)s.A)[512 + tid] = zz;
  }
  __syncthreads();
  if (tid < 32) s.A[tid * 232 + 204] = (_Float16)1.f;
  const int t0 = d ? (TT - 1) : 0;
  *(uint2*)&s.A[sao0] = *(const uint2*)&h0w[sgo0 + t0 * 4352];
  *(uint2*)&s.A[sao1] = *(const uint2*)&h0w[sgo1 + t0 * 4352];
  if (tid < 64) *(uint2*)&s.A[sao2] = *(const uint2*)&h0w[sgo2 + t0 * 4352];
  if (tid < 340) s.fcwt[0][tid] = fcw[fk2 * 6528 + t0 * 136 + d * 68 + fj];
  __syncthreads();

  #pragma unroll 1
  for (int st = 0; st < TT; ++st) {
    const int t  = d ? (TT - 1 - st) : st;
    const int tn = d ? (t - 1) : (t + 1);

    f32x4 aL0 = {0.f,0.f,0.f,0.f}, aH0 = {0.f,0.f,0.f,0.f};
    f32x4 aL1 = {0.f,0.f,0.f,0.f}, aH1 = {0.f,0.f,0.f,0.f};
    f32x4 a2  = {0.f,0.f,0.f,0.f};
    #pragma unroll
    for (int kk = 0; kk < 7; ++kk) {
      const half8 alo = *(const half8*)&s.A[lr * 232 + kk * 32 + lq * 8];
      const half8 ahi = *(const half8*)&s.A[(lr + 16) * 232 + kk * 32 + lq * 8];
      aL0 = __builtin_amdgcn_mfma_f32_16x16x32_f16(alo, Bf[0][kk], aL0, 0, 0, 0);
      aH0 = __builtin_amdgcn_mfma_f32_16x16x32_f16(ahi, Bf[0][kk], aH0, 0, 0, 0);
      aL1 = __builtin_amdgcn_mfma_f32_16x16x32_f16(alo, Bf[1][kk], aL1, 0, 0, 0);
      aH1 = __builtin_amdgcn_mfma_f32_16x16x32_f16(ahi, Bf[1][kk], aH1, 0, 0, 0);
      if (wid < 2) {
        const half8 bb = *(const half8*)&s.u.bx[(kk * 64 + ln) * 8];
        const half8 av = (wid == 0) ? alo : ahi;
        a2 = __builtin_amdgcn_mfma_f32_16x16x32_f16(av, bb, a2, 0, 0, 0);
      }
    }
    {
      const int g0 = (wid * 2) * 16 + lr;
      #pragma unroll
      for (int r = 0; r < 4; ++r) {
        s.gates[(lq * 4 + r) * GSTR + g0]            = aL0[r];
        s.gates[(16 + lq * 4 + r) * GSTR + g0]       = aH0[r];
        s.gates[(lq * 4 + r) * GSTR + g0 + 16]       = aL1[r];
        s.gates[(16 + lq * 4 + r) * GSTR + g0 + 16]  = aH1[r];
      }
      if (wid < 2) {
        #pragma unroll
        for (int r = 0; r < 4; ++r)
          s.gates[(16 * wid + lq * 4 + r) * GSTR + 256 + lr] = a2[r];
      }
    }
    __syncthreads();

    {
      const int b = tid >> 4, jb = tid & 15;
      const int gb = b * GSTR;
      #pragma unroll
      for (int q = 0; q < 5; ++q) {
        if (q < 4 || jb < 4) {
          const int j = (q < 4) ? (jb + 16 * q) : (64 + jb);
          const float gi = s.gates[gb + j];
          const float gf = s.gates[gb + 68 + j];
          const float gg = s.gates[gb + 136 + j];
          const float go = s.gates[gb + 204 + j];
          const float ii = sigm(gi), ff = sigm(gf), g2 = tanh_s(gg), oo = sigm(go);
          const float cc = ff * cst[q] + ii * g2;
          cst[q] = cc;
          const float h = oo * tanh_s(cc);
          s.A[b * 232 + 136 + j] = (_Float16)h;
          #pragma unroll
          for (int k = 0; k < 5; ++k) yk[k] += h * s.fcwt[st & 1][k * 68 + j];
        }
      }
    }
    // staging (direct global->LDS; latency hidden by co-resident block)
    if (st < TT - 1) {
      *(uint2*)&s.A[sao0] = *(const uint2*)&h0w[sgo0 + tn * 4352];
      *(uint2*)&s.A[sao1] = *(const uint2*)&h0w[sgo1 + tn * 4352];
      if (tid < 64) *(uint2*)&s.A[sao2] = *(const uint2*)&h0w[sgo2 + tn * 4352];
      if (tid < 340) s.fcwt[(st + 1) & 1][tid] = fcw[fk2 * 6528 + tn * 136 + d * 68 + fj];
    }
    __syncthreads();
  }

  // FC partial: butterfly over 16 threads sharing b, write ypart[g][d][b][k]
  #pragma unroll
  for (int m = 1; m < 16; m <<= 1) {
    #pragma unroll
    for (int k = 0; k < 5; ++k) yk[k] += __shfl_xor(yk[k], m, 64);
  }
  if ((tid & 15) == 0) {
    const int b = tid >> 4;
    #pragma unroll
    for (int k = 0; k < 5; ++k)
      ypart[((size_t)g * 2 + d) * 160 + b * 5 + k] = yk[k];
  }
}

//==================== kernel C: combine partials ====================
__global__ void fc_combine(const float* __restrict__ ypart,
                           const float* __restrict__ fcb,
                           float* __restrict__ out)
{
  const int i = blockIdx.x * 256 + threadIdx.x;
  if (i < NSEQ * 5) {
    const int k = i % 5;
    const int gb = i / 5;            // g*32 + b
    const int g = gb >> 5, b = gb & 31;
    out[i] = fcb[k] + ypart[((size_t)g * 2 + 0) * 160 + b * 5 + k]
                    + ypart[((size_t)g * 2 + 1) * 160 + b * 5 + k];
  }
}

extern "C" void kernel_launch(void* const* d_in, const int* in_sizes, int n_in,
                              void* d_out, int out_size, void* d_ws, size_t ws_size,
                              hipStream_t stream) {
  (void)in_sizes; (void)n_in; (void)out_size;
  static_assert(sizeof(SmemL0) <= 64 * 1024, "L0 LDS");
  static_assert(sizeof(SmemL1) <= 64 * 1024, "L1 LDS");

  const float* x     = (const float*)d_in[0];
  const float* Wih0f = (const float*)d_in[1];
  const float* Whh0f = (const float*)d_in[2];
  const float* bih0f = (const float*)d_in[3];
  const float* bhh0f = (const float*)d_in[4];
  const float* Wih0b = (const float*)d_in[5];
  const float* Whh0b = (const float*)d_in[6];
  const float* bih0b = (const float*)d_in[7];
  const float* bhh0b = (const float*)d_in[8];
  const float* Wih1f = (const float*)d_in[9];
  const float* Whh1f = (const float*)d_in[10];
  const float* bih1f = (const float*)d_in[11];
  const float* bhh1f = (const float*)d_in[12];
  const float* Wih1b = (const float*)d_in[13];
  const float* Whh1b = (const float*)d_in[14];
  const float* bih1b = (const float*)d_in[15];
  const float* bhh1b = (const float*)d_in[16];
  const float* fcw   = (const float*)d_in[17];
  const float* fcb   = (const float*)d_in[18];
  float* out = (float*)d_out;

  // carve ypart from the tail of ws; slices for h0 from the head
  const size_t ypart_bytes = (size_t)YPART_FLOATS * 4;
  size_t ypart_off = (ws_size > ypart_bytes) ? ((ws_size - ypart_bytes) & ~(size_t)15) : 0;
  float* ypart = (float*)((char*)d_ws + ypart_off);
  long long chunk_ll = (long long)(ypart_off / SLICE_B);
  int chunk = (int)(chunk_ll < 1 ? 1 : (chunk_ll > NGRP ? NGRP : chunk_ll));
  _Float16* slices = (_Float16*)d_ws;

  for (int c0 = 0; c0 < NGRP; c0 += chunk) {
    const int n = (NGRP - c0 < chunk) ? (NGRP - c0) : chunk;
    l0_pass<<<dim3(2 * n), dim3(NTHR), 0, stream>>>(x,
        Wih0f, Whh0f, bih0f, bhh0f, Wih0b, Whh0b, bih0b, bhh0b,
        slices, c0);
    l1_pass<<<dim3(2 * n), dim3(NTHR), 0, stream>>>(
        Wih1f, Whh1f, bih1f, bhh1f, Wih1b, Whh1b, bih1b, bhh1b,
        fcw, slices, ypart, c0);
  }
  fc_combine<<<dim3((NSEQ * 5 + 255) / 256), dim3(256), 0, stream>>>(ypart, fcb, out);
}

// Round 25
// 711.363 us; speedup vs baseline: 1.6368x; 1.1045x over previous
//
#include <hip/hip_runtime.h>

typedef _Float16 half8 __attribute__((ext_vector_type(8)));
typedef float f32x4 __attribute__((ext_vector_type(4)));

#define TT 48
#define BT 32
#define NSEQ 16384
#define NGRP (NSEQ / BT)            // 512 groups
#define NTHR 512
#define GSTR 276                    // gates row stride (b-major); 276%32=20 -> ~2-way banks
#define SLICE_E (TT * BT * 136)     // 208896 f16 elems per group h0 slice
#define SLICE_B (SLICE_E * 2)       // 417792 bytes
#define YPART_FLOATS (NGRP * 2 * BT * 5)   // 163840 floats = 655360 B

__device__ __forceinline__ float fast_rcp(float v) { return __builtin_amdgcn_rcpf(v); }
__device__ __forceinline__ float sigm(float v)  { return fast_rcp(1.f + __expf(-v)); }
__device__ __forceinline__ float tanh_s(float v){ return 1.f - 2.f * fast_rcp(1.f + __expf(2.f * v)); }

//==================== kernel A: layer-0, one (group,dir) per block ====================
struct __align__(16) SmemL0 {
  float gates[32 * GSTR];       // 35328 B
  _Float16 A[32 * 136];         //  8704 B  [x(34) | h(68) | pad | bias@102 ...]
  _Float16 bx[4 * 64 * 8];      //  4096 B  tile-16 B fragments
};                              // 48128 B

__global__ __attribute__((amdgpu_flat_work_group_size(NTHR, NTHR)))
void l0_pass(const float* __restrict__ x,
    const float* __restrict__ WihF, const float* __restrict__ WhhF,
    const float* __restrict__ bihF, const float* __restrict__ bhhF,
    const float* __restrict__ WihB, const float* __restrict__ WhhB,
    const float* __restrict__ bihB, const float* __restrict__ bhhB,
    _Float16* __restrict__ ws, int c0)
{
  __shared__ SmemL0 s;
  const int tid = threadIdx.x;
  const int ln = tid & 63, wid = tid >> 6;
  const int lr = ln & 15, lq = ln >> 4;
  const int g_loc = blockIdx.x >> 1, d = blockIdx.x & 1;
  _Float16* h0w = ws + (size_t)g_loc * SLICE_E;
  const float* xg = x + (size_t)(c0 + g_loc) * (BT * TT * 34);
  const float* Wih = d ? WihB : WihF;
  const float* Whh = d ? WhhB : WhhF;
  const float* bih = d ? bihB : bihF;
  const float* bhh = d ? bhhB : bhhF;

  // reg B fragments: 2 tiles/wave, K = 128 (x|h|bias)
  half8 Bf[2][4];
  #pragma unroll
  for (int i = 0; i < 2; ++i) {
    const int g = (wid * 2 + i) * 16 + lr;
    #pragma unroll
    for (int kk = 0; kk < 4; ++kk) {
      half8 v;
      #pragma unroll
      for (int j = 0; j < 8; ++j) {
        const int k = kk * 32 + lq * 8 + j;
        float wv = 0.f;
        if (k < 34) wv = Wih[g * 34 + k];
        else if (k < 102) wv = Whh[g * 68 + (k - 34)];
        else if (k == 102) wv = bih[g] + bhh[g];
        v[j] = (_Float16)wv;
      }
      Bf[i][kk] = v;
    }
  }
  if (tid < 4 * 64) {
    const int kk = tid >> 6, l2 = tid & 63;
    const int g = 256 + (l2 & 15);
    half8 v;
    #pragma unroll
    for (int j = 0; j < 8; ++j) {
      const int k = kk * 32 + ((l2 >> 4) & 3) * 8 + j;
      float wv = 0.f;
      if (k < 34) wv = Wih[g * 34 + k];
      else if (k < 102) wv = Whh[g * 68 + (k - 34)];
      else if (k == 102) wv = bih[g] + bhh[g];
      v[j] = (_Float16)wv;
    }
    *(half8*)&s.bx[tid * 8] = v;
  }

  float cst[5];
  #pragma unroll
  for (int q = 0; q < 5; ++q) cst[q] = 0.f;

  // staging offsets: 1088 = 32b x 34i tasks
  int sgo0, sao0, sgo1, sao1, sgo2, sao2;
  { const int b = tid / 34, i = tid % 34;
    sgo0 = b * (TT * 34) + i;  sao0 = b * 136 + i; }
  { const int t1 = tid + 512, b = t1 / 34, i = t1 % 34;
    sgo1 = b * (TT * 34) + i;  sao1 = b * 136 + i; }
  { const int t2 = (tid < 64) ? (tid + 1024) : 1024, b = t2 / 34, i = t2 % 34;
    sgo2 = b * (TT * 34) + i;  sao2 = b * 136 + i; }

  // prologue: zero A (544 uint4), bias col, stage step 0
  {
    const uint4 zz = {0, 0, 0, 0};
    ((uint4*)s.A)[tid] = zz;
    if (tid < 32) ((uint4*)s.A)[512 + tid] = zz;
  }
  __syncthreads();
  if (tid < 32) s.A[tid * 136 + 102] = (_Float16)1.f;
  const int t0 = d ? (TT - 1) : 0;
  s.A[sao0] = (_Float16)xg[sgo0 + t0 * 34];
  s.A[sao1] = (_Float16)xg[sgo1 + t0 * 34];
  if (tid < 64) s.A[sao2] = (_Float16)xg[sgo2 + t0 * 34];
  __syncthreads();

  #pragma unroll 1
  for (int st = 0; st < TT; ++st) {
    const int t  = d ? (TT - 1 - st) : st;
    const int tn = d ? (t - 1) : (t + 1);

    float xp0 = 0.f, xp1 = 0.f, xp2 = 0.f;
    if (st < TT - 1) {
      xp0 = xg[sgo0 + tn * 34];
      xp1 = xg[sgo1 + tn * 34];
      if (tid < 64) xp2 = xg[sgo2 + tn * 34];
    }

    f32x4 aL0 = {0.f,0.f,0.f,0.f}, aH0 = {0.f,0.f,0.f,0.f};
    f32x4 aL1 = {0.f,0.f,0.f,0.f}, aH1 = {0.f,0.f,0.f,0.f};
    f32x4 a2  = {0.f,0.f,0.f,0.f};
    #pragma unroll
    for (int kk = 0; kk < 4; ++kk) {
      const half8 alo = *(const half8*)&s.A[lr * 136 + kk * 32 + lq * 8];
      const half8 ahi = *(const half8*)&s.A[(lr + 16) * 136 + kk * 32 + lq * 8];
      aL0 = __builtin_amdgcn_mfma_f32_16x16x32_f16(alo, Bf[0][kk], aL0, 0, 0, 0);
      aH0 = __builtin_amdgcn_mfma_f32_16x16x32_f16(ahi, Bf[0][kk], aH0, 0, 0, 0);
      aL1 = __builtin_amdgcn_mfma_f32_16x16x32_f16(alo, Bf[1][kk], aL1, 0, 0, 0);
      aH1 = __builtin_amdgcn_mfma_f32_16x16x32_f16(ahi, Bf[1][kk], aH1, 0, 0, 0);
      if (wid < 2) {
        const half8 bb = *(const half8*)&s.bx[(kk * 64 + ln) * 8];
        const half8 av = (wid == 0) ? alo : ahi;
        a2 = __builtin_amdgcn_mfma_f32_16x16x32_f16(av, bb, a2, 0, 0, 0);
      }
    }
    {
      const int g0 = (wid * 2) * 16 + lr;
      #pragma unroll
      for (int r = 0; r < 4; ++r) {
        s.gates[(lq * 4 + r) * GSTR + g0]            = aL0[r];
        s.gates[(16 + lq * 4 + r) * GSTR + g0]       = aH0[r];
        s.gates[(lq * 4 + r) * GSTR + g0 + 16]       = aL1[r];
        s.gates[(16 + lq * 4 + r) * GSTR + g0 + 16]  = aH1[r];
      }
      if (wid < 2) {
        #pragma unroll
        for (int r = 0; r < 4; ++r)
          s.gates[(16 * wid + lq * 4 + r) * GSTR + 256 + lr] = a2[r];
      }
    }
    __syncthreads();

    {
      const int b = tid >> 4, jb = tid & 15;
      const int gb = b * GSTR;
      #pragma unroll
      for (int q = 0; q < 5; ++q) {
        if (q < 4 || jb < 4) {
          const int j = (q < 4) ? (jb + 16 * q) : (64 + jb);
          const float gi = s.gates[gb + j];
          const float gf = s.gates[gb + 68 + j];
          const float gg = s.gates[gb + 136 + j];
          const float go = s.gates[gb + 204 + j];
          const float ii = sigm(gi), ff = sigm(gf), g2 = tanh_s(gg), oo = sigm(go);
          const float cc = ff * cst[q] + ii * g2;
          cst[q] = cc;
          const float h = oo * tanh_s(cc);
          const _Float16 h16 = (_Float16)h;
          s.A[b * 136 + 34 + j] = h16;
          h0w[t * 4352 + d * 2176 + b * 68 + j] = h16;
        }
      }
    }
    if (st < TT - 1) {
      s.A[sao0] = (_Float16)xp0;
      s.A[sao1] = (_Float16)xp1;
      if (tid < 64) s.A[sao2] = (_Float16)xp2;
    }
    __syncthreads();
  }
}

//==================== kernel B: layer-1 + FC partial, one (group,dir) per block ====================
struct __align__(16) SmemL1 {
  float gates[32 * GSTR];       // 35328 B
  _Float16 A[32 * 232];         // 14848 B  [h0(136) | h1(68) | pad | bias@204 ...]
  union {
    _Float16 bx[7 * 64 * 8];    //  7168 B
    float ysc[160];
  } u;
  float fcwt[2][340];           //  2720 B
};                              // 60064 B

__global__ __attribute__((amdgpu_flat_work_group_size(NTHR, NTHR)))
void l1_pass(
    const float* __restrict__ WihF, const float* __restrict__ WhhF,
    const float* __restrict__ bihF, const float* __restrict__ bhhF,
    const float* __restrict__ WihB, const float* __restrict__ WhhB,
    const float* __restrict__ bihB, const float* __restrict__ bhhB,
    const float* __restrict__ fcw,
    _Float16* __restrict__ ws, float* __restrict__ ypart, int c0)
{
  __shared__ SmemL1 s;
  const int tid = threadIdx.x;
  const int ln = tid & 63, wid = tid >> 6;
  const int lr = ln & 15, lq = ln >> 4;
  const int g_loc = blockIdx.x >> 1, d = blockIdx.x & 1;
  const int g = c0 + g_loc;
  _Float16* h0w = ws + (size_t)g_loc * SLICE_E;
  const float* Wih = d ? WihB : WihF;
  const float* Whh = d ? WhhB : WhhF;
  const float* bih = d ? bihB : bihF;
  const float* bhh = d ? bhhB : bhhF;

  // reg B fragments: 2 tiles/wave, K = 224 (h0|h1|bias)
  half8 Bf[2][7];
  #pragma unroll
  for (int i = 0; i < 2; ++i) {
    const int gg_ = (wid * 2 + i) * 16 + lr;
    #pragma unroll
    for (int kk = 0; kk < 7; ++kk) {
      half8 v;
      #pragma unroll
      for (int j = 0; j < 8; ++j) {
        const int k = kk * 32 + lq * 8 + j;
        float wv = 0.f;
        if (k < 136) wv = Wih[gg_ * 136 + k];
        else if (k < 204) wv = Whh[gg_ * 68 + (k - 136)];
        else if (k == 204) wv = bih[gg_] + bhh[gg_];
        v[j] = (_Float16)wv;
      }
      Bf[i][kk] = v;
    }
  }
  if (tid < 7 * 64) {
    const int kk = tid / 64, l2 = tid & 63;
    const int gg_ = 256 + (l2 & 15);
    half8 v;
    #pragma unroll
    for (int j = 0; j < 8; ++j) {
      const int k = kk * 32 + ((l2 >> 4) & 3) * 8 + j;
      float wv = 0.f;
      if (k < 136) wv = Wih[gg_ * 136 + k];
      else if (k < 204) wv = Whh[gg_ * 68 + (k - 136)];
      else if (k == 204) wv = bih[gg_] + bhh[gg_];
      v[j] = (_Float16)wv;
    }
    *(half8*)&s.u.bx[tid * 8] = v;
  }

  float cst[5], yk[5];
  #pragma unroll
  for (int q = 0; q < 5; ++q) { cst[q] = 0.f; yk[q] = 0.f; }

  // staging offsets: 1088 = 2dd x 32b x 17c (uint2 chunks of h0 row)
  int sgo0, sao0, sgo1, sao1, sgo2, sao2;
  { const int dd = tid / 544, r = tid % 544, b = r / 17, c = r % 17;
    sgo0 = dd * 2176 + b * 68 + c * 4;  sao0 = b * 232 + dd * 68 + c * 4; }
  { const int t1 = tid + 512, dd = t1 / 544, r = t1 % 544, b = r / 17, c = r % 17;
    sgo1 = dd * 2176 + b * 68 + c * 4;  sao1 = b * 232 + dd * 68 + c * 4; }
  { const int t2 = (tid < 64) ? (tid + 1024) : 1024, dd = t2 / 544, r = t2 % 544,
      b = r / 17, c = r % 17;
    sgo2 = dd * 2176 + b * 68 + c * 4;  sao2 = b * 232 + dd * 68 + c * 4; }
  int fk2 = 0, fj = 0;
  if (tid < 340) { fk2 = tid / 68; fj = tid % 68; }

  // prologue: zero A (928 uint4), bias col, stage step 0 + fcwt[0]
  {
    const uint4 zz = {0, 0, 0, 0};
    ((uint4*)s.A)[tid] = zz;
    if (tid < 416) ((uint4*)s.A)[512 + tid] = zz;
  }
  __syncthreads();
  if (tid < 32) s.A[tid * 232 + 204] = (_Float16)1.f;
  const int t0 = d ? (TT - 1) : 0;
  *(uint2*)&s.A[sao0] = *(const uint2*)&h0w[sgo0 + t0 * 4352];
  *(uint2*)&s.A[sao1] = *(const uint2*)&h0w[sgo1 + t0 * 4352];
  if (tid < 64) *(uint2*)&s.A[sao2] = *(const uint2*)&h0w[sgo2 + t0 * 4352];
  if (tid < 340) s.fcwt[0][tid] = fcw[fk2 * 6528 + t0 * 136 + d * 68 + fj];
  __syncthreads();

  #pragma unroll 1
  for (int st = 0; st < TT; ++st) {
    const int t  = d ? (TT - 1 - st) : st;
    const int tn = d ? (t - 1) : (t + 1);

    // ---- prefetch next step's staging into registers (hides HBM/L2 latency) ----
    uint2 hp0 = {0, 0}, hp1 = {0, 0}, hp2 = {0, 0};
    float fwp = 0.f;
    if (st < TT - 1) {
      hp0 = *(const uint2*)&h0w[sgo0 + tn * 4352];
      hp1 = *(const uint2*)&h0w[sgo1 + tn * 4352];
      if (tid < 64) hp2 = *(const uint2*)&h0w[sgo2 + tn * 4352];
      if (tid < 340) fwp = fcw[fk2 * 6528 + tn * 136 + d * 68 + fj];
    }

    f32x4 aL0 = {0.f,0.f,0.f,0.f}, aH0 = {0.f,0.f,0.f,0.f};
    f32x4 aL1 = {0.f,0.f,0.f,0.f}, aH1 = {0.f,0.f,0.f,0.f};
    f32x4 a2  = {0.f,0.f,0.f,0.f};
    #pragma unroll
    for (int kk = 0; kk < 7; ++kk) {
      const half8 alo = *(const half8*)&s.A[lr * 232 + kk * 32 + lq * 8];
      const half8 ahi = *(const half8*)&s.A[(lr + 16) * 232 + kk * 32 + lq * 8];
      aL0 = __builtin_amdgcn_mfma_f32_16x16x32_f16(alo, Bf[0][kk], aL0, 0, 0, 0);
      aH0 = __builtin_amdgcn_mfma_f32_16x16x32_f16(ahi, Bf[0][kk], aH0, 0, 0, 0);
      aL1 = __builtin_amdgcn_mfma_f32_16x16x32_f16(alo, Bf[1][kk], aL1, 0, 0, 0);
      aH1 = __builtin_amdgcn_mfma_f32_16x16x32_f16(ahi, Bf[1][kk], aH1, 0, 0, 0);
      if (wid < 2) {
        const half8 bb = *(const half8*)&s.u.bx[(kk * 64 + ln) * 8];
        const half8 av = (wid == 0) ? alo : ahi;
        a2 = __builtin_amdgcn_mfma_f32_16x16x32_f16(av, bb, a2, 0, 0, 0);
      }
    }
    {
      const int g0 = (wid * 2) * 16 + lr;
      #pragma unroll
      for (int r = 0; r < 4; ++r) {
        s.gates[(lq * 4 + r) * GSTR + g0]            = aL0[r];
        s.gates[(16 + lq * 4 + r) * GSTR + g0]       = aH0[r];
        s.gates[(lq * 4 + r) * GSTR + g0 + 16]       = aL1[r];
        s.gates[(16 + lq * 4 + r) * GSTR + g0 + 16]  = aH1[r];
      }
      if (wid < 2) {
        #pragma unroll
        for (int r = 0; r < 4; ++r)
          s.gates[(16 * wid + lq * 4 + r) * GSTR + 256 + lr] = a2[r];
      }
    }
    __syncthreads();

    {
      const int b = tid >> 4, jb = tid & 15;
      const int gb = b * GSTR;
      #pragma unroll
      for (int q = 0; q < 5; ++q) {
        if (q < 4 || jb < 4) {
          const int j = (q < 4) ? (jb + 16 * q) : (64 + jb);
          const float gi = s.gates[gb + j];
          const float gf = s.gates[gb + 68 + j];
          const float gg = s.gates[gb + 136 + j];
          const float go = s.gates[gb + 204 + j];
          const float ii = sigm(gi), ff = sigm(gf), g2 = tanh_s(gg), oo = sigm(go);
          const float cc = ff * cst[q] + ii * g2;
          cst[q] = cc;
          const float h = oo * tanh_s(cc);
          s.A[b * 232 + 136 + j] = (_Float16)h;
          #pragma unroll
          for (int k = 0; k < 5; ++k) yk[k] += h * s.fcwt[st & 1][k * 68 + j];
        }
      }
    }
    // commit prefetched staging to LDS
    if (st < TT - 1) {
      *(uint2*)&s.A[sao0] = hp0;
      *(uint2*)&s.A[sao1] = hp1;
      if (tid < 64) *(uint2*)&s.A[sao2] = hp2;
      if (tid < 340) s.fcwt[(st + 1) & 1][tid] = fwp;
    }
    __syncthreads();
  }

  // FC partial: butterfly over 16 threads sharing b, write ypart[g][d][b][k]
  #pragma unroll
  for (int m = 1; m < 16; m <<= 1) {
    #pragma unroll
    for (int k = 0; k < 5; ++k) yk[k] += __shfl_xor(yk[k], m, 64);
  }
  if ((tid & 15) == 0) {
    const int b = tid >> 4;
    #pragma unroll
    for (int k = 0; k < 5; ++k)
      ypart[((size_t)g * 2 + d) * 160 + b * 5 + k] = yk[k];
  }
}

//==================== kernel C: combine partials ====================
__global__ void fc_combine(const float* __restrict__ ypart,
                           const float* __restrict__ fcb,
                           float* __restrict__ out)
{
  const int i = blockIdx.x * 256 + threadIdx.x;
  if (i < NSEQ * 5) {
    const int k = i % 5;
    const int gb = i / 5;            // g*32 + b
    const int g = gb >> 5, b = gb & 31;
    out[i] = fcb[k] + ypart[((size_t)g * 2 + 0) * 160 + b * 5 + k]
                    + ypart[((size_t)g * 2 + 1) * 160 + b * 5 + k];
  }
}

extern "C" void kernel_launch(void* const* d_in, const int* in_sizes, int n_in,
                              void* d_out, int out_size, void* d_ws, size_t ws_size,
                              hipStream_t stream) {
  (void)in_sizes; (void)n_in; (void)out_size;
  static_assert(sizeof(SmemL0) <= 64 * 1024, "L0 LDS");
  static_assert(sizeof(SmemL1) <= 64 * 1024, "L1 LDS");

  const float* x     = (const float*)d_in[0];
  const float* Wih0f = (const float*)d_in[1];
  const float* Whh0f = (const float*)d_in[2];
  const float* bih0f = (const float*)d_in[3];
  const float* bhh0f = (const float*)d_in[4];
  const float* Wih0b = (const float*)d_in[5];
  const float* Whh0b = (const float*)d_in[6];
  const float* bih0b = (const float*)d_in[7];
  const float* bhh0b = (const float*)d_in[8];
  const float* Wih1f = (const float*)d_in[9];
  const float* Whh1f = (const float*)d_in[10];
  const float* bih1f = (const float*)d_in[11];
  const float* bhh1f = (const float*)d_in[12];
  const float* Wih1b = (const float*)d_in[13];
  const float* Whh1b = (const float*)d_in[14];
  const float* bih1b = (const float*)d_in[15];
  const float* bhh1b = (const float*)d_in[16];
  const float* fcw   = (const float*)d_in[17];
  const float* fcb   = (const float*)d_in[18];
  float* out = (float*)d_out;

  // carve ypart from the tail of ws; slices for h0 from the head
  const size_t ypart_bytes = (size_t)YPART_FLOATS * 4;
  size_t ypart_off = (ws_size > ypart_bytes) ? ((ws_size - ypart_bytes) & ~(size_t)15) : 0;
  float* ypart = (float*)((char*)d_ws + ypart_off);
  long long chunk_ll = (long long)(ypart_off / SLICE_B);
  int chunk = (int)(chunk_ll < 1 ? 1 : (chunk_ll > NGRP ? NGRP : chunk_ll));
  _Float16* slices = (_Float16*)d_ws;

  for (int c0 = 0; c0 < NGRP; c0 += chunk) {
    const int n = (NGRP - c0 < chunk) ? (NGRP - c0) : chunk;
    l0_pass<<<dim3(2 * n), dim3(NTHR), 0, stream>>>(x,
        Wih0f, Whh0f, bih0f, bhh0f, Wih0b, Whh0b, bih0b, bhh0b,
        slices, c0);
    l1_pass<<<dim3(2 * n), dim3(NTHR), 0, stream>>>(
        Wih1f, Whh1f, bih1f, bhh1f, Wih1b, Whh1b, bih1b, bhh1b,
        fcw, slices, ypart, c0);
  }
  fc_combine<<<dim3((NSEQ * 5 + 255) / 256), dim3(256), 0, stream>>>(ypart, fcb, out);
}